// Round 16
// baseline (25.895 us; speedup 1.0000x reference)
//
#include <hip/hip_runtime.h>
#include <math.h>

#define B_    32
#define PPB   256
#define N_    (B_*PPB)     // 8192 proposals / padded slots
#define M_    128
#define LANG_ 256
#define H_    128
#define EPS_  1e-5f
#define MC    32           // columns per MLP block
#define NBLK  (N_/MC)      // 256 blocks (>= CU count)
#define WR    132          // padded LDS weight-row stride (bf16 elems)

typedef __attribute__((ext_vector_type(8))) short s16x8;
typedef __attribute__((ext_vector_type(4))) float f32x4;
typedef unsigned long long ull_t;

static __device__ __forceinline__ unsigned short f2bf(float x) {
  unsigned int u = __float_as_uint(x);
  unsigned int r = (u + 0x7fff + ((u >> 16) & 1)) >> 16;
  return (unsigned short)r;
}
static __device__ __forceinline__ float bf2f(unsigned short h) {
  return __uint_as_float(((unsigned int)h) << 16);
}

// ---------------------------------------------------------------------------
// Kernel P: 64 blocks, two disjoint roles (wa build REMOVED — weights are
// now converted inside k_mlp from the clean read-only originals):
//   blk  0-31: fp_c gather for chunk blk
//   blk 32-63: lang projection for batch blk-32
// ---------------------------------------------------------------------------
__global__ __launch_bounds__(256) void k_prep(
    const int* __restrict__ pidx, const int* __restrict__ poff,
    int* __restrict__ fp_c,
    const float* __restrict__ Wf, const float* __restrict__ lang,
    float* __restrict__ lp)
{
  const int tid = threadIdx.x;
  const int blk = blockIdx.x;

  if (blk < 32) {
    const int i = blk * 256 + tid;
    const int off = poff[i];
    fp_c[i] = pidx[2 * off + 1];
  } else {
    const int bb = blk - 32;
    const int o = tid >> 1, hf = tid & 1;
    float acc = 0.f;
    const int l0 = hf * 128;
    #pragma unroll 8
    for (int l = l0; l < l0 + 128; l += 4) {
      const float4 w = *reinterpret_cast<const float4*>(Wf + o * 384 + 128 + l);
      const float4 e = *reinterpret_cast<const float4*>(lang + bb * LANG_ + l);
      acc += w.x * e.x + w.y * e.y + w.z * e.z + w.w * e.w;
    }
    acc += __shfl_xor(acc, 1);
    if (hf == 0) lp[bb * H_ + o] = acc;
  }
}

// ---------------------------------------------------------------------------
// Kernel D: MFMA MLP (r13 body/geometry) with weights staged per-layer from
// the ORIGINAL fp32 arrays (clean lines, L2-warm across graph replays)
// through LDS, converted to hi/lo bf16 in-kernel. No producer-written wa.
// 256 blocks x 512 threads, MC=32, 8 waves/CU.
// ---------------------------------------------------------------------------
#define WLOAD(Wsrc, STRIDE)                                                  \
  {                                                                          \
    const float* rp = (Wsrc) + (size_t)wr * (STRIDE) + wq * 32;              \
    _Pragma("unroll")                                                        \
    for (int i2 = 0; i2 < 8; ++i2)                                           \
      wld[i2] = *reinterpret_cast<const float4*>(rp + 4 * i2);               \
  }

#define WSTORE()                                                             \
  {                                                                          \
    const int wbase = wr * WR + wq * 32;                                     \
    _Pragma("unroll")                                                        \
    for (int i2 = 0; i2 < 8; ++i2) {                                         \
      ull_t hv64 = 0, lv64 = 0;                                              \
      const float ve[4] = {wld[i2].x, wld[i2].y, wld[i2].z, wld[i2].w};      \
      _Pragma("unroll")                                                      \
      for (int e = 0; e < 4; ++e) {                                          \
        const unsigned short h = f2bf(ve[e]);                                \
        const unsigned short l = f2bf(ve[e] - bf2f(h));                      \
        hv64 |= (ull_t)h << (16 * e);                                        \
        lv64 |= (ull_t)l << (16 * e);                                        \
      }                                                                      \
      *reinterpret_cast<ull_t*>(&WHi[wbase + i2 * 4]) = hv64;                \
      *reinterpret_cast<ull_t*>(&WLo[wbase + i2 * 4]) = lv64;                \
    }                                                                        \
  }

#define READ_A(Aarr)                                                         \
  {                                                                          \
    const int ob = (wid * 16 + o16) * WR;                                    \
    _Pragma("unroll")                                                        \
    for (int sp = 0; sp < 4; ++sp) {                                         \
      const int ia = ob + sp * 32 + g * 4;                                   \
      union { ull_t u[2]; s16x8 v; } uh, ul;                                 \
      uh.u[0] = *reinterpret_cast<const ull_t*>(&WHi[ia]);                   \
      uh.u[1] = *reinterpret_cast<const ull_t*>(&WHi[ia + 16]);              \
      ul.u[0] = *reinterpret_cast<const ull_t*>(&WLo[ia]);                   \
      ul.u[1] = *reinterpret_cast<const ull_t*>(&WLo[ia + 16]);              \
      Aarr[sp] = uh.v;                                                       \
      Aarr[4 + sp] = ul.v;                                                   \
    }                                                                        \
  }

#define READ_B()                                                             \
  {                                                                          \
    _Pragma("unroll")                                                        \
    for (int s = 0; s < 4; ++s)                                              \
      _Pragma("unroll")                                                      \
      for (int nt = 0; nt < 2; ++nt) {                                       \
        const int idx = (s * 4 + g) * 32 + nt * 16 + o16;                    \
        Bh[s][nt] = XbHi[idx];                                               \
        Bl[s][nt] = XbLo[idx];                                               \
      }                                                                      \
  }

#define MFMA_LAYER(Aarr)                                                     \
  {                                                                          \
    _Pragma("unroll")                                                        \
    for (int sg = 0; sg < 8; ++sg)                                           \
      _Pragma("unroll")                                                      \
      for (int nt = 0; nt < 2; ++nt) {                                       \
        const s16x8 bb = (sg < 4) ? Bh[sg][nt] : Bl[sg - 4][nt];             \
        acc[nt] = __builtin_amdgcn_mfma_f32_16x16x32_bf16(Aarr[sg], bb, acc[nt], 0, 0, 0); \
      }                                                                      \
    _Pragma("unroll")                                                        \
    for (int sg = 0; sg < 8; ++sg)                                           \
      _Pragma("unroll")                                                      \
      for (int nt = 0; nt < 2; ++nt) {                                       \
        const s16x8 bb = (sg < 4) ? Bl[sg][nt] : Bh[sg - 4][nt];             \
        acc[nt] = __builtin_amdgcn_mfma_f32_16x16x32_bf16(Aarr[sg], bb, acc[nt], 0, 0, 0); \
      }                                                                      \
  }

#define ACT_STORE(EXPR_V)                                                    \
  {                                                                          \
    _Pragma("unroll")                                                        \
    for (int nt = 0; nt < 2; ++nt) {                                         \
      ull_t hv64 = 0, lv64 = 0;                                              \
      _Pragma("unroll")                                                      \
      for (int r = 0; r < 4; ++r) {                                          \
        const int o = wid * 16 + g * 4 + r;                                  \
        const float z = acc[nt][r];                                          \
        const float v = (EXPR_V);                                            \
        const unsigned short h = f2bf(v);                                    \
        const unsigned short l = f2bf(v - bf2f(h));                          \
        hv64 |= (ull_t)h << (16 * r);                                        \
        lv64 |= (ull_t)l << (16 * r);                                        \
      }                                                                      \
      const int f = ((wid >> 1) * 4 + g) * 32 + nt * 16 + o16;               \
      reinterpret_cast<ull_t*>(XbHi)[f * 2 + (wid & 1)] = hv64;              \
      reinterpret_cast<ull_t*>(XbLo)[f * 2 + (wid & 1)] = lv64;              \
    }                                                                        \
  }

__global__ __launch_bounds__(512, 1) void k_mlp(
    const float* __restrict__ feats,
    const float* __restrict__ Wf, const float* __restrict__ W1,
    const float* __restrict__ W2,
    const int* __restrict__ fp_c, const int* __restrict__ boff,
    const float* __restrict__ bf, const float* __restrict__ b1,
    const float* __restrict__ g1, const float* __restrict__ be1,
    const float* __restrict__ rm1, const float* __restrict__ rv1,
    const float* __restrict__ b2, const float* __restrict__ g2,
    const float* __restrict__ be2, const float* __restrict__ rm2,
    const float* __restrict__ rv2,
    const float* __restrict__ W3, const float* __restrict__ b3,
    const float* __restrict__ lpg,
    float* __restrict__ out)
{
  __shared__ unsigned short WHi[128 * WR];   // 33.8 KB
  __shared__ unsigned short WLo[128 * WR];   // 33.8 KB
  __shared__ s16x8 XbHi[512];                // 8 KB
  __shared__ s16x8 XbLo[512];                // 8 KB
  __shared__ float pbuf[1024];               // 4 KB
  __shared__ float outp[8][32];
  __shared__ int   sSrow[MC];
  __shared__ int   wtot[8];

  const int tid = threadIdx.x;     // 0..511
  const int lane = tid & 63, wid = tid >> 6;   // 8 waves
  const int o16 = lane & 15, g = lane >> 4;
  const int wr = tid >> 2, wq = tid & 3;       // weight staging: row, quarter
  const int q0 = blockIdx.x * MC;
  const int b = q0 >> 8;           // 8 blocks per batch
  const int r0 = q0 & 255;         // within-batch column window start

  // ---- issue layer-0 weight loads first (in flight under mapping + pbuf)
  float4 wld[8];
  WLOAD(Wf, 384);

  // ---- mapping (r13 verbatim): derive 32 srcmap entries from fp_c
  if (tid < MC) sSrow[tid] = -1;
  const int blo = boff[b], bhi = boff[b + 1];
  const int i0 = tid * 16;
  unsigned mask = 0u;
  #pragma unroll
  for (int jj = 0; jj < 4; ++jj) {
    const int4 pv = *reinterpret_cast<const int4*>(fp_c + i0 + jj * 4);
    const int fps[4] = {pv.x, pv.y, pv.z, pv.w};
    #pragma unroll
    for (int e = 0; e < 4; ++e)
      mask |= (fps[e] >= blo && fps[e] < bhi) ? (1u << (jj * 4 + e)) : 0u;
  }
  const int cnt = __popc(mask);
  int sc = cnt;                    // inclusive wave scan
  #pragma unroll
  for (int d = 1; d < 64; d <<= 1) {
    const int v = __shfl_up(sc, d);
    if (lane >= d) sc += v;
  }
  if (lane == 63) wtot[wid] = sc;
  __syncthreads();                 // sSrow init + wtot visible
  int base = sc - cnt;
  #pragma unroll
  for (int w = 0; w < 8; ++w) if (w < wid) base += wtot[w];
  {
    unsigned m = mask;
    int r = base;
    while (m) {
      const int j = __ffs(m) - 1;
      if (r >= r0 && r < r0 + MC) sSrow[r - r0] = i0 + j;
      ++r;
      m &= m - 1;
    }
  }

  // ---- pbuf (BN folds etc., reads clean inputs only)
  #pragma unroll
  for (int j = tid; j < 1024; j += 512) {
    const int arr = j >> 7, o = j & 127;
    float v;
    switch (arr) {
      case 0: v = bf[o] + lpg[b * H_ + o]; break;
      case 1: v = b1[o]; break;
      case 2: v = g1[o] * rsqrtf(rv1[o] + EPS_); break;
      case 3: { const float s = g1[o] * rsqrtf(rv1[o] + EPS_);
                v = be1[o] - rm1[o] * s; } break;
      case 4: v = b2[o]; break;
      case 5: v = g2[o] * rsqrtf(rv2[o] + EPS_); break;
      case 6: { const float s = g2[o] * rsqrtf(rv2[o] + EPS_);
                v = be2[o] - rm2[o] * s; } break;
      default: v = W3[o]; break;
    }
    pbuf[j] = v;
  }
  __syncthreads();                 // sSrow writes + pbuf visible

  // ---- gather feats (hi/lo split) into Xb; convert+store staged W0
  {
    const int n = tid & 31, u = tid >> 5;
    const int s = u >> 2, gg = u & 3;
    const int srow = sSrow[n];
    const int k0 = s * 32 + gg * 4;
    float4 a = make_float4(0.f, 0.f, 0.f, 0.f), bq = a;
    if (srow >= 0) {
      a  = *reinterpret_cast<const float4*>(feats + (size_t)srow * M_ + k0);
      bq = *reinterpret_cast<const float4*>(feats + (size_t)srow * M_ + k0 + 16);
    }
    const float av[8] = {a.x, a.y, a.z, a.w, bq.x, bq.y, bq.z, bq.w};
    s16x8 hv, lv;
    #pragma unroll
    for (int e = 0; e < 8; ++e) {
      const unsigned short h = f2bf(av[e]);
      hv[e] = (short)h;
      lv[e] = (short)f2bf(av[e] - bf2f(h));
    }
    XbHi[u * 32 + n] = hv;
    XbLo[u * 32 + n] = lv;
  }
  WSTORE();                        // W0 -> LDS (hi/lo bf16)
  __syncthreads();

  f32x4 acc[2];
  s16x8 A[8];
  s16x8 Bh[4][2], Bl[4][2];

  // ================= Layer 0 =================
  READ_A(A);
  READ_B();
  WLOAD(W1, H_);                   // next-layer loads in flight under MFMA
  acc[0] = (f32x4){0.f, 0.f, 0.f, 0.f};
  acc[1] = (f32x4){0.f, 0.f, 0.f, 0.f};
  MFMA_LAYER(A);
  __syncthreads();                 // all frag reads done
  ACT_STORE(fmaxf(z + pbuf[o], 0.f));
  WSTORE();                        // W1 -> LDS
  __syncthreads();

  // ================= Layer 1 =================
  READ_A(A);
  READ_B();
  WLOAD(W2, H_);
  acc[0] = (f32x4){0.f, 0.f, 0.f, 0.f};
  acc[1] = (f32x4){0.f, 0.f, 0.f, 0.f};
  MFMA_LAYER(A);
  __syncthreads();
  ACT_STORE(fmaxf(z + pbuf[128 + o], 0.f) * pbuf[256 + o] + pbuf[384 + o]);
  WSTORE();                        // W2 -> LDS
  __syncthreads();

  // ================= Layer 2 + epilogue =================
  READ_A(A);
  READ_B();
  acc[0] = (f32x4){0.f, 0.f, 0.f, 0.f};
  acc[1] = (f32x4){0.f, 0.f, 0.f, 0.f};
  MFMA_LAYER(A);
  {
    float p0 = 0.f, p1 = 0.f;
    #pragma unroll
    for (int r = 0; r < 4; ++r) {
      const int o = wid * 16 + g * 4 + r;
      const float w3 = pbuf[896 + o];
      const float bb2 = pbuf[512 + o], ss2 = pbuf[640 + o], tt2 = pbuf[768 + o];
      p0 += w3 * (fmaxf(acc[0][r] + bb2, 0.f) * ss2 + tt2);
      p1 += w3 * (fmaxf(acc[1][r] + bb2, 0.f) * ss2 + tt2);
    }
    p0 += __shfl_xor(p0, 16); p0 += __shfl_xor(p0, 32);
    p1 += __shfl_xor(p1, 16); p1 += __shfl_xor(p1, 32);
    if (lane < 16) {
      outp[wid][o16] = p0;
      outp[wid][16 + o16] = p1;
    }
    __syncthreads();
    if (tid < 32) {
      float s = b3[0];
      #pragma unroll
      for (int w = 0; w < 8; ++w) s += outp[w][tid];
      out[q0 + tid] = s;
    }
  }
}

// ---------------------------------------------------------------------------
extern "C" void kernel_launch(void* const* d_in, const int* in_sizes, int n_in,
                              void* d_out, int out_size, void* d_ws, size_t ws_size,
                              hipStream_t stream) {
  const float* feats = (const float*)d_in[0];
  const int*   pidx  = (const int*)d_in[1];
  const int*   poff  = (const int*)d_in[2];
  const int*   boff  = (const int*)d_in[3];
  const float* lang  = (const float*)d_in[4];
  const float* Wf    = (const float*)d_in[5];
  const float* bf    = (const float*)d_in[6];
  const float* W1    = (const float*)d_in[7];
  const float* b1    = (const float*)d_in[8];
  const float* g1    = (const float*)d_in[9];
  const float* be1   = (const float*)d_in[10];
  const float* rm1   = (const float*)d_in[11];
  const float* rv1   = (const float*)d_in[12];
  const float* W2    = (const float*)d_in[13];
  const float* b2    = (const float*)d_in[14];
  const float* g2    = (const float*)d_in[15];
  const float* be2   = (const float*)d_in[16];
  const float* rm2   = (const float*)d_in[17];
  const float* rv2   = (const float*)d_in[18];
  const float* W3    = (const float*)d_in[19];
  const float* b3    = (const float*)d_in[20];
  float* out = (float*)d_out;

  int*   fp_c = (int*)d_ws;                          // 32768 B
  float* lp   = (float*)((char*)d_ws + 32768);       // 16384 B

  hipLaunchKernelGGL(k_prep, dim3(64), dim3(256), 0, stream,
                     pidx, poff, fp_c, Wf, lang, lp);
  hipLaunchKernelGGL(k_mlp, dim3(NBLK), dim3(512), 0, stream,
                     feats, Wf, W1, W2, fp_c, boff, bf, b1, g1, be1, rm1, rv1,
                     b2, g2, be2, rm2, rv2, W3, b3, lp, out);
}

// Round 17
// 20.536 us; speedup vs baseline: 1.2610x; 1.2610x over previous
//
#include <hip/hip_runtime.h>
#include <math.h>

#define B_    32
#define PPB   256
#define N_    (B_*PPB)     // 8192 proposals / padded slots
#define M_    128
#define LANG_ 256
#define H_    128
#define EPS_  1e-5f
#define MC    32           // columns per MLP block
#define NBLK  (N_/MC)      // 256 blocks (>= CU count)

typedef __attribute__((ext_vector_type(8))) short s16x8;
typedef __attribute__((ext_vector_type(4))) float f32x4;
typedef unsigned long long ull_t;

static __device__ __forceinline__ unsigned short f2bf(float x) {
  unsigned int u = __float_as_uint(x);
  unsigned int r = (u + 0x7fff + ((u >> 16) & 1)) >> 16;
  return (unsigned short)r;
}
static __device__ __forceinline__ float bf2f(unsigned short h) {
  return __uint_as_float(((unsigned int)h) << 16);
}

// ---------------------------------------------------------------------------
// Kernel P (r13 structure): 96 blocks, three disjoint roles. ALL producer
// outputs written with NON-TEMPORAL stores so the lines are CLEAN (L3) when
// k_mlp's 8 XCDs read them — avoids dirty-owner L2 serialization.
// ---------------------------------------------------------------------------
__global__ __launch_bounds__(256) void k_prep(
    const int* __restrict__ pidx, const int* __restrict__ poff,
    int* __restrict__ fp_c,
    const float* __restrict__ Wf, const float* __restrict__ lang,
    float* __restrict__ lp,
    const float* __restrict__ W1, const float* __restrict__ W2,
    unsigned short* __restrict__ wa)
{
  const int tid = threadIdx.x;
  const int lane = tid & 63, wid = tid >> 6;
  const int o16 = lane & 15, g = lane >> 4;
  const int blk = blockIdx.x;

  if (blk < 32) {
    const int i = blk * 256 + tid;
    const int off = poff[i];
    __builtin_nontemporal_store(pidx[2 * off + 1], &fp_c[i]);
  } else if (blk < 64) {
    const int bb = blk - 32;
    const int o = tid >> 1, hf = tid & 1;
    float acc = 0.f;
    const int l0 = hf * 128;
    #pragma unroll 8
    for (int l = l0; l < l0 + 128; l += 4) {
      const float4 w = *reinterpret_cast<const float4*>(Wf + o * 384 + 128 + l);
      const float4 e = *reinterpret_cast<const float4*>(lang + bb * LANG_ + l);
      acc += w.x * e.x + w.y * e.y + w.z * e.z + w.w * e.w;
    }
    acc += __shfl_xor(acc, 1);
    if (hf == 0) __builtin_nontemporal_store(acc, &lp[bb * H_ + o]);
  } else {
    for (int sub = wid; sub < 6; sub += 4) {
      const int G = (blk - 64) * 6 + sub;
      const int L = G >> 6, s = (G >> 3) & 7, t = G & 7;
      const float* Wsrc; int str;
      if (L == 0)      { Wsrc = Wf; str = 384; }
      else if (L == 1) { Wsrc = W1; str = H_; }
      else             { Wsrc = W2; str = H_; }
      const int o = t * 16 + o16, sp = s & 3;
      const bool hi = (s < 4);
      const float* rowp = Wsrc + (size_t)o * str + sp * 32 + g * 4;
      const float4 a = *reinterpret_cast<const float4*>(rowp);
      const float4 bq = *reinterpret_cast<const float4*>(rowp + 16);
      const float av[8] = {a.x, a.y, a.z, a.w, bq.x, bq.y, bq.z, bq.w};
      union { s16x8 v; ull_t u[2]; } cv;
      #pragma unroll
      for (int e = 0; e < 8; ++e) {
        const unsigned short h = f2bf(av[e]);
        cv.v[e] = (short)(hi ? h : f2bf(av[e] - bf2f(h)));
      }
      ull_t* wp = reinterpret_cast<ull_t*>(wa + (size_t)G * 512 + lane * 8);
      __builtin_nontemporal_store(cv.u[0], wp);
      __builtin_nontemporal_store(cv.u[1], wp + 1);
    }
  }
}

// ---------------------------------------------------------------------------
// Kernel D (r13 verbatim): MFMA MLP, MC=32, 256 blocks x 512 threads.
// ---------------------------------------------------------------------------
#define LOAD_A(Aarr, LL)                                                     \
  {                                                                          \
    _Pragma("unroll")                                                        \
    for (int s = 0; s < 8; ++s)                                              \
      Aarr[s] = *reinterpret_cast<const s16x8*>(                             \
          wa + (size_t)(((LL) * 8 + s) * 8 + wid) * 512 + lane * 8);         \
  }

#define READ_B()                                                             \
  {                                                                          \
    _Pragma("unroll")                                                        \
    for (int s = 0; s < 4; ++s)                                              \
      _Pragma("unroll")                                                      \
      for (int nt = 0; nt < 2; ++nt) {                                       \
        const int idx = (s * 4 + g) * 32 + nt * 16 + o16;                    \
        Bh[s][nt] = XbHi[idx];                                               \
        Bl[s][nt] = XbLo[idx];                                               \
      }                                                                      \
  }

#define MFMA_LAYER(Aarr)                                                     \
  {                                                                          \
    _Pragma("unroll")                                                        \
    for (int sg = 0; sg < 8; ++sg)                                           \
      _Pragma("unroll")                                                      \
      for (int nt = 0; nt < 2; ++nt) {                                       \
        const s16x8 bb = (sg < 4) ? Bh[sg][nt] : Bl[sg - 4][nt];             \
        acc[nt] = __builtin_amdgcn_mfma_f32_16x16x32_bf16(Aarr[sg], bb, acc[nt], 0, 0, 0); \
      }                                                                      \
    _Pragma("unroll")                                                        \
    for (int sg = 0; sg < 8; ++sg)                                           \
      _Pragma("unroll")                                                      \
      for (int nt = 0; nt < 2; ++nt) {                                       \
        const s16x8 bb = (sg < 4) ? Bl[sg][nt] : Bh[sg - 4][nt];             \
        acc[nt] = __builtin_amdgcn_mfma_f32_16x16x32_bf16(Aarr[sg], bb, acc[nt], 0, 0, 0); \
      }                                                                      \
  }

#define ACT_STORE(EXPR_V)                                                    \
  {                                                                          \
    _Pragma("unroll")                                                        \
    for (int nt = 0; nt < 2; ++nt) {                                         \
      ull_t hv64 = 0, lv64 = 0;                                              \
      _Pragma("unroll")                                                      \
      for (int r = 0; r < 4; ++r) {                                          \
        const int o = wid * 16 + g * 4 + r;                                  \
        const float z = acc[nt][r];                                          \
        const float v = (EXPR_V);                                            \
        const unsigned short h = f2bf(v);                                    \
        const unsigned short l = f2bf(v - bf2f(h));                          \
        hv64 |= (ull_t)h << (16 * r);                                        \
        lv64 |= (ull_t)l << (16 * r);                                        \
      }                                                                      \
      const int f = ((wid >> 1) * 4 + g) * 32 + nt * 16 + o16;               \
      reinterpret_cast<ull_t*>(XbHi)[f * 2 + (wid & 1)] = hv64;              \
      reinterpret_cast<ull_t*>(XbLo)[f * 2 + (wid & 1)] = lv64;              \
    }                                                                        \
  }

__global__ __launch_bounds__(512, 2) void k_mlp(
    const float* __restrict__ feats,
    const unsigned short* __restrict__ wa,
    const int* __restrict__ fp_c, const int* __restrict__ boff,
    const float* __restrict__ bf, const float* __restrict__ b1,
    const float* __restrict__ g1, const float* __restrict__ be1,
    const float* __restrict__ rm1, const float* __restrict__ rv1,
    const float* __restrict__ b2, const float* __restrict__ g2,
    const float* __restrict__ be2, const float* __restrict__ rm2,
    const float* __restrict__ rv2,
    const float* __restrict__ W3, const float* __restrict__ b3,
    const float* __restrict__ lpg,
    float* __restrict__ out)
{
  __shared__ s16x8 XbHi[512];      // [u16][n32] frags (8 KB)
  __shared__ s16x8 XbLo[512];      // (8 KB)
  __shared__ float pbuf[1024];     // (4 KB)
  __shared__ float outp[8][32];
  __shared__ int   sSrow[MC];
  __shared__ int   wtot[8];

  const int tid = threadIdx.x;     // 0..511
  const int lane = tid & 63, wid = tid >> 6;   // 8 waves
  const int o16 = lane & 15, g = lane >> 4;
  const int q0 = blockIdx.x * MC;
  const int b = q0 >> 8;           // 8 blocks per batch
  const int r0 = q0 & 255;         // within-batch column window start

  // ---- derive this block's 32 srcmap entries from compact fp_c
  if (tid < MC) sSrow[tid] = -1;
  const int blo = boff[b], bhi = boff[b + 1];
  const int i0 = tid * 16;
  unsigned mask = 0u;
  #pragma unroll
  for (int jj = 0; jj < 4; ++jj) {
    const int4 pv = *reinterpret_cast<const int4*>(fp_c + i0 + jj * 4);
    const int fps[4] = {pv.x, pv.y, pv.z, pv.w};
    #pragma unroll
    for (int e = 0; e < 4; ++e)
      mask |= (fps[e] >= blo && fps[e] < bhi) ? (1u << (jj * 4 + e)) : 0u;
  }
  const int cnt = __popc(mask);
  int sc = cnt;                    // inclusive wave scan
  #pragma unroll
  for (int d = 1; d < 64; d <<= 1) {
    const int v = __shfl_up(sc, d);
    if (lane >= d) sc += v;
  }
  if (lane == 63) wtot[wid] = sc;
  __syncthreads();                 // sSrow init + wtot visible
  int base = sc - cnt;
  #pragma unroll
  for (int w = 0; w < 8; ++w) if (w < wid) base += wtot[w];
  {
    unsigned m = mask;
    int r = base;
    while (m) {
      const int j = __ffs(m) - 1;
      if (r >= r0 && r < r0 + MC) sSrow[r - r0] = i0 + j;
      ++r;
      m &= m - 1;
    }
  }

  // ---- layer-0 A-frags in flight under pbuf
  s16x8 A0[8], A1[8], A2[8];
  LOAD_A(A0, 0);

  #pragma unroll
  for (int j = tid; j < 1024; j += 512) {
    const int arr = j >> 7, o = j & 127;
    float v;
    switch (arr) {
      case 0: v = bf[o] + lpg[b * H_ + o]; break;
      case 1: v = b1[o]; break;
      case 2: v = g1[o] * rsqrtf(rv1[o] + EPS_); break;
      case 3: { const float s = g1[o] * rsqrtf(rv1[o] + EPS_);
                v = be1[o] - rm1[o] * s; } break;
      case 4: v = b2[o]; break;
      case 5: v = g2[o] * rsqrtf(rv2[o] + EPS_); break;
      case 6: { const float s = g2[o] * rsqrtf(rv2[o] + EPS_);
                v = be2[o] - rm2[o] * s; } break;
      default: v = W3[o]; break;
    }
    pbuf[j] = v;
  }
  __syncthreads();                 // sSrow writes + pbuf visible

  // ---- gather feats (hi/lo split) into Xb: frag u x col n
  {
    const int n = tid & 31, u = tid >> 5;
    const int s = u >> 2, gg = u & 3;
    const int srow = sSrow[n];
    const int k0 = s * 32 + gg * 4;
    float4 a = make_float4(0.f, 0.f, 0.f, 0.f), bq = a;
    if (srow >= 0) {
      a  = *reinterpret_cast<const float4*>(feats + (size_t)srow * M_ + k0);
      bq = *reinterpret_cast<const float4*>(feats + (size_t)srow * M_ + k0 + 16);
    }
    const float av[8] = {a.x, a.y, a.z, a.w, bq.x, bq.y, bq.z, bq.w};
    s16x8 hv, lv;
    #pragma unroll
    for (int e = 0; e < 8; ++e) {
      const unsigned short h = f2bf(av[e]);
      hv[e] = (short)h;
      lv[e] = (short)f2bf(av[e] - bf2f(h));
    }
    XbHi[u * 32 + n] = hv;
    XbLo[u * 32 + n] = lv;
  }
  __syncthreads();

  f32x4 acc[2];
  s16x8 Bh[4][2], Bl[4][2];

  // ================= Layer 0 =================
  READ_B();
  __syncthreads();
  LOAD_A(A1, 1);
  acc[0] = (f32x4){0.f, 0.f, 0.f, 0.f};
  acc[1] = (f32x4){0.f, 0.f, 0.f, 0.f};
  MFMA_LAYER(A0);
  ACT_STORE(fmaxf(z + pbuf[o], 0.f));
  __syncthreads();

  // ================= Layer 1 =================
  READ_B();
  __syncthreads();
  LOAD_A(A2, 2);
  acc[0] = (f32x4){0.f, 0.f, 0.f, 0.f};
  acc[1] = (f32x4){0.f, 0.f, 0.f, 0.f};
  MFMA_LAYER(A1);
  ACT_STORE(fmaxf(z + pbuf[128 + o], 0.f) * pbuf[256 + o] + pbuf[384 + o]);
  __syncthreads();

  // ================= Layer 2 + epilogue =================
  READ_B();
  acc[0] = (f32x4){0.f, 0.f, 0.f, 0.f};
  acc[1] = (f32x4){0.f, 0.f, 0.f, 0.f};
  MFMA_LAYER(A2);
  {
    float p0 = 0.f, p1 = 0.f;
    #pragma unroll
    for (int r = 0; r < 4; ++r) {
      const int o = wid * 16 + g * 4 + r;
      const float w3 = pbuf[896 + o];
      const float bb2 = pbuf[512 + o], ss2 = pbuf[640 + o], tt2 = pbuf[768 + o];
      p0 += w3 * (fmaxf(acc[0][r] + bb2, 0.f) * ss2 + tt2);
      p1 += w3 * (fmaxf(acc[1][r] + bb2, 0.f) * ss2 + tt2);
    }
    p0 += __shfl_xor(p0, 16); p0 += __shfl_xor(p0, 32);
    p1 += __shfl_xor(p1, 16); p1 += __shfl_xor(p1, 32);
    if (lane < 16) {
      outp[wid][o16] = p0;
      outp[wid][16 + o16] = p1;
    }
    __syncthreads();
    if (tid < 32) {
      float s = b3[0];
      #pragma unroll
      for (int w = 0; w < 8; ++w) s += outp[w][tid];
      out[q0 + tid] = s;
    }
  }
}

// ---------------------------------------------------------------------------
extern "C" void kernel_launch(void* const* d_in, const int* in_sizes, int n_in,
                              void* d_out, int out_size, void* d_ws, size_t ws_size,
                              hipStream_t stream) {
  const float* feats = (const float*)d_in[0];
  const int*   pidx  = (const int*)d_in[1];
  const int*   poff  = (const int*)d_in[2];
  const int*   boff  = (const int*)d_in[3];
  const float* lang  = (const float*)d_in[4];
  const float* Wf    = (const float*)d_in[5];
  const float* bf    = (const float*)d_in[6];
  const float* W1    = (const float*)d_in[7];
  const float* b1    = (const float*)d_in[8];
  const float* g1    = (const float*)d_in[9];
  const float* be1   = (const float*)d_in[10];
  const float* rm1   = (const float*)d_in[11];
  const float* rv1   = (const float*)d_in[12];
  const float* W2    = (const float*)d_in[13];
  const float* b2    = (const float*)d_in[14];
  const float* g2    = (const float*)d_in[15];
  const float* be2   = (const float*)d_in[16];
  const float* rm2   = (const float*)d_in[17];
  const float* rv2   = (const float*)d_in[18];
  const float* W3    = (const float*)d_in[19];
  const float* b3    = (const float*)d_in[20];
  float* out = (float*)d_out;

  int*            fp_c = (int*)d_ws;                               // 32768 B
  float*          lp   = (float*)((char*)d_ws + 32768);            // 16384 B
  unsigned short* wa   = (unsigned short*)((char*)d_ws + 49152);   // 196608 B

  hipLaunchKernelGGL(k_prep, dim3(96), dim3(256), 0, stream,
                     pidx, poff, fp_c, Wf, lang, lp, W1, W2, wa);
  hipLaunchKernelGGL(k_mlp, dim3(NBLK), dim3(512), 0, stream,
                     feats, wa, fp_c, boff, bf, b1, g1, be1, rm1, rv1,
                     b2, g2, be2, rm2, rv2, W3, b3, lp, out);
}